// Round 2
// baseline (69.920 us; speedup 1.0000x reference)
//
#include <hip/hip_runtime.h>

// GraphAggrMLPv2: out[n,m,h] = relu(zW1[n,h] + (x^T W2)[m,h] + b[h])
//   z:[8192,128] x:[128,128] W:[256,4] b:[4] fp32 -> out:[8192,128,4] fp32
// Window is dominated by harness ops (256MiB ws poison ~41.4us @81% HBM peak
// + out poison + restores + graph overhead); kernel-controllable share ~5-7us,
// memory floor ~3.3us (4MiB z in + 16MiB out). 2-kernel split measured 1us
// WORSE (launch overhead) => single launch, 1024 blocks x 256 threads
// (4 blocks/CU), 8 z-rows/block, redundant per-block xW (x is L2-resident).
// This rev (UNMEASURED — 2x GPU acquisition timeout; resubmitted verbatim):
// (1) drop 3rd barrier + tvec LDS round-trip (combine computed redundantly
// per-thread); (2) nontemporal loads for z / stores for out so the 16MiB
// stream-out doesn't evict the block-shared x (64KB, read by all 1024 blocks)
// from the 4MiB/XCD L2.

union F4 { float4 v; float f[4]; };

// native vector type for __builtin_nontemporal_* (HIP float4 is a struct)
typedef float nf4 __attribute__((ext_vector_type(4)));

// LDS bank swizzle for W rows (phase-C reads are d-strided float4s).
__device__ __forceinline__ int sw(int r) { return r + (r >> 3); }

__global__ void __launch_bounds__(256) gam_fused(
    const float* __restrict__ z, const float* __restrict__ x,
    const float* __restrict__ W, const float* __restrict__ b,
    float4* __restrict__ out4)
{
    __shared__ float4 Wf[292];        // swizzled [256 rows][4 heads]
    __shared__ float4 tpart[2][128];  // xW partials (two d-halves)
    __shared__ float4 zw[8];          // zW for this block's 8 rows

    const int t   = threadIdx.x;
    const int blk = blockIdx.x;

    // ---- z slice: 8 rows x 128 = 256 float4, one per thread (NT: single use)
    const float4* zp = (const float4*)(z + (size_t)blk * 8 * 128);
    F4 a0;
    {
        nf4 zt = __builtin_nontemporal_load((const nf4*)(zp + t));
        a0.v = make_float4(zt.x, zt.y, zt.z, zt.w);
    }

    // b is 16B, broadcast, L2-hit — issue early to hide latency.
    const float4 bv = *(const float4*)b;

    // ---- W -> LDS (swizzled) ----
    Wf[sw(t)] = ((const float4*)W)[t];
    __syncthreads();

    // ---- phase A: xW partials t[m][h] = sum_d x[d][m]*W2[d][h] ----
    // m = t&127, half = t>>7; x column reads coalesced, L2-resident.
    {
        const int m    = t & 127;
        const int half = t >> 7;
        const float* xp = x + (size_t)(half * 64) * 128 + m;
        float4 acc = make_float4(0.f, 0.f, 0.f, 0.f);
#pragma unroll 8
        for (int dd = 0; dd < 64; ++dd) {
            float  xv = xp[dd * 128];
            float4 w  = Wf[sw(128 + half * 64 + dd)];  // wave-uniform broadcast
            acc.x = fmaf(xv, w.x, acc.x);
            acc.y = fmaf(xv, w.y, acc.y);
            acc.z = fmaf(xv, w.z, acc.z);
            acc.w = fmaf(xv, w.w, acc.w);
        }
        tpart[half][m] = acc;
    }

    // ---- phase C: zW for 8 rows; 32 lanes (same t>>5) share a row ----
    {
        const int d0 = (t & 31) * 4;
        float4 p0 = make_float4(0.f, 0.f, 0.f, 0.f);
#pragma unroll
        for (int j = 0; j < 4; ++j) {
            float4 w = Wf[sw(d0 + j)];   // W1 rows
            p0.x = fmaf(a0.f[j], w.x, p0.x);
            p0.y = fmaf(a0.f[j], w.y, p0.y);
            p0.z = fmaf(a0.f[j], w.z, p0.z);
            p0.w = fmaf(a0.f[j], w.w, p0.w);
        }
#pragma unroll
        for (int off = 16; off; off >>= 1) {   // stays in 32-lane row-groups
            p0.x += __shfl_xor(p0.x, off);
            p0.y += __shfl_xor(p0.y, off);
            p0.z += __shfl_xor(p0.z, off);
            p0.w += __shfl_xor(p0.w, off);
        }
        if ((t & 31) == 0) zw[t >> 5] = p0;
    }
    __syncthreads();

    // ---- combine (redundant per-thread, no 3rd barrier):
    //      tq = tpart0[m] + tpart1[m] + b, m = t&127 ----
    float4 tq;
    {
        const int m = t & 127;
        const float4 q0 = tpart[0][m];   // ds_read_b128, sequential, no conflict
        const float4 q1 = tpart[1][m];
        tq.x = q0.x + q1.x + bv.x;
        tq.y = q0.y + q1.y + bv.y;
        tq.z = q0.z + q1.z + bv.z;
        tq.w = q0.w + q1.w + bv.w;
    }

    // ---- phase D: out4[row][m] = relu(tq + zw[row]) ----
    // chunk c = it*256+t: row = it*2+(t>>7) (wave-uniform), m = t&127 invariant
    {
        float4* op = out4 + (size_t)blk * 1024;   // 8 rows x 128 float4
#pragma unroll
        for (int it = 0; it < 4; ++it) {
            const int row = it * 2 + (t >> 7);
            const float4 s = zw[row];              // LDS broadcast
            nf4 v;
            v.x = fmaxf(tq.x + s.x, 0.f);
            v.y = fmaxf(tq.y + s.y, 0.f);
            v.z = fmaxf(tq.z + s.z, 0.f);
            v.w = fmaxf(tq.w + s.w, 0.f);
            __builtin_nontemporal_store(v, (nf4*)(op + it * 256 + t));
        }
    }
}

extern "C" void kernel_launch(void* const* d_in, const int* in_sizes, int n_in,
                              void* d_out, int out_size, void* d_ws, size_t ws_size,
                              hipStream_t stream) {
    const float* z = (const float*)d_in[0];
    const float* x = (const float*)d_in[1];
    const float* W = (const float*)d_in[2];
    const float* b = (const float*)d_in[3];
    gam_fused<<<1024, 256, 0, stream>>>(z, x, W, b, (float4*)d_out);
}